// Round 7
// baseline (111.658 us; speedup 1.0000x reference)
//
#include <hip/hip_runtime.h>
#include <cstdint>

// ---------------- compile-time DCT tables (butterfly-packed) ----------------
// __device__ constexpr: initializers are compiler-visible, every coefficient
// folds to a 32-bit literal operand on v_fmac_f32 — zero s_loads at runtime.
constexpr double kPI  = 3.14159265358979323846264338327950288;
constexpr double kLN2 = 0.69314718055994530941723212145818;
constexpr double cos_poly(double x) {            // |x| <= pi/2, Taylor
    double x2 = x * x, term = 1.0, sum = 1.0;
    for (int n = 1; n <= 13; ++n) { term *= -x2 / double((2 * n - 1) * (2 * n)); sum += term; }
    return sum;
}
constexpr double cos_idx(int a) {                // cos(a*pi/64), a mod 128
    a &= 127;
    if (a <= 32)  return  cos_poly(a * kPI / 64.0);
    if (a <= 64)  return -cos_poly((64 - a) * kPI / 64.0);
    if (a <= 96)  return -cos_poly((a - 64) * kPI / 64.0);
    return cos_poly((128 - a) * kPI / 64.0);
}
constexpr double csqrt(double v) {
    double x = 1.0;
    for (int i = 0; i < 60; ++i) x = 0.5 * (x + v / x);
    return x;
}
constexpr float Dij(int i, int j) {              // D[i][j], 32-point DCT-II
    double sc = (i == 0) ? csqrt(1.0 / 32.0) : 0.25;   // sqrt(2/32) == 0.25 exactly
    int a = ((2 * j + 1) * i) & 127;
    return (float)(sc * cos_idx(a));
}
// Fold identities (all exact for DCT-II):
//   D32[i][31-k]   = (-1)^i D32[i][k]        -> e/o split
//   D32[2m][15-k]  = (-1)^m D32[2m][k]       -> ee/eo split
//   D32[4m][7-k]   = (-1)^m D32[4m][k]       -> eee/eeo split
struct OddT { float d[256]; };                   // rows 2m+1 on o[16]
constexpr OddT make_odd() { OddT t{}; for (int m = 0; m < 16; ++m) for (int k = 0; k < 16; ++k) t.d[m*16+k] = Dij(2*m+1, k); return t; }
struct E8T { float d[64]; };                     // rows 4m+2 on eo[8]
constexpr E8T make_e2() { E8T t{}; for (int m = 0; m < 8; ++m) for (int k = 0; k < 8; ++k) t.d[m*8+k] = Dij(4*m+2, k); return t; }
struct E4T { float d[16]; };
constexpr E4T make_ee() { E4T t{}; for (int m = 0; m < 4; ++m) for (int k = 0; k < 4; ++k) t.d[m*4+k] = Dij(8*m,   k); return t; }   // rows 8t on eee[4]
constexpr E4T make_eo() { E4T t{}; for (int m = 0; m < 4; ++m) for (int k = 0; k < 4; ++k) t.d[m*4+k] = Dij(8*m+4, k); return t; }   // rows 8t+4 on eeo[4]
struct FTab { float f[64]; };
constexpr FTab make_F() {                        // f(s) = ln2 * sum_g [s in band g] 2^g/n_g
    FTab t{};                                    // (ln2 folded in: we use log2 instead of ln)
    const int lo[6] = {0, 11, 22, 32, 43, 54};
    const int hi[6] = {10, 21, 32, 42, 53, 62};  // s=32 in bands 2 AND 3 (fp64 boundary = 32.0)
    const int n [6] = {66, 187, 306, 286, 165, 45};
    for (int s = 0; s < 64; ++s) {
        double acc = 0.0, w = 1.0;
        for (int g = 0; g < 6; ++g) { if (s >= lo[g] && s <= hi[g]) acc += w / double(n[g]); w *= 2.0; }
        t.f[s] = (float)(acc * kLN2);
    }
    return t;
}
__device__ constexpr OddT cOdd = make_odd();
__device__ constexpr E8T  cE2  = make_e2();
__device__ constexpr E4T  cEE  = make_ee();
__device__ constexpr E4T  cEO  = make_eo();
__device__ constexpr FTab cF   = make_F();

#define NP  15376   // 16 * 961 patches
#define NPC 46128   // NP * 3 (patch, channel) tasks
#define LPB 961     // 31*31 patches per batch image
#define SST 34      // LDS stride: write bank=(2j+lane) c-free; b64 read bank=2(lane+h),
                    // only lanes l/l+16 alias (2-way = free, m136); 8B-aligned (136|8)

// 32-point DCT-II, 3 butterfly stages, IN-PLACE: 352 FMA + 56 add, peak live
// set stays ~v[32]+chains (~40 VGPR) instead of ~80 -> no scratch spills.
// After folds: o[k]=v[31-k], eo[k]=v[15-k], eee[k]=v[k], eeo[k]=v[7-k].
template <typename EMIT>
__device__ __forceinline__ void dct32(float* __restrict__ v, EMIT&& emit) {
    #pragma unroll
    for (int k = 0; k < 16; ++k) { float a = v[k], b = v[31-k]; v[k] = a + b; v[31-k] = a - b; }
    #pragma unroll
    for (int k = 0; k < 8; ++k)  { float a = v[k], b = v[15-k]; v[k] = a + b; v[15-k] = a - b; }
    #pragma unroll
    for (int k = 0; k < 4; ++k)  { float a = v[k], b = v[7-k];  v[k] = a + b; v[7-k]  = a - b; }
    #pragma unroll
    for (int m = 0; m < 16; m += 2) {            // odd rows 2m+1 on o[k]=v[31-k]: 2 chains
        float a = 0.f, b = 0.f;
        #pragma unroll
        for (int k = 0; k < 16; ++k) {
            a = fmaf(cOdd.d[m*16+k],     v[31-k], a);
            b = fmaf(cOdd.d[(m+1)*16+k], v[31-k], b);
        }
        emit(2*m+1, a); emit(2*m+3, b);
    }
    #pragma unroll
    for (int m = 0; m < 8; m += 2) {             // rows 4m+2 on eo[k]=v[15-k]: 2 chains
        float a = 0.f, b = 0.f;
        #pragma unroll
        for (int k = 0; k < 8; ++k) {
            a = fmaf(cE2.d[m*8+k],     v[15-k], a);
            b = fmaf(cE2.d[(m+1)*8+k], v[15-k], b);
        }
        emit(4*m+2, a); emit(4*m+6, b);
    }
    {                                            // rows 8t on eee[k]=v[k], 8t+4 on eeo[k]=v[7-k]
        float a0=0.f,a1=0.f,a2=0.f,a3=0.f,b0=0.f,b1=0.f,b2=0.f,b3=0.f;
        #pragma unroll
        for (int k = 0; k < 4; ++k) {
            a0 = fmaf(cEE.d[0*4+k], v[k],   a0);
            a1 = fmaf(cEE.d[1*4+k], v[k],   a1);
            a2 = fmaf(cEE.d[2*4+k], v[k],   a2);
            a3 = fmaf(cEE.d[3*4+k], v[k],   a3);
            b0 = fmaf(cEO.d[0*4+k], v[7-k], b0);
            b1 = fmaf(cEO.d[1*4+k], v[7-k], b1);
            b2 = fmaf(cEO.d[2*4+k], v[7-k], b2);
            b3 = fmaf(cEO.d[3*4+k], v[7-k], b3);
        }
        emit(0, a0); emit(8, a1); emit(16, a2); emit(24, a3);
        emit(4, b0); emit(12, b1); emit(20, b2); emit(28, b3);
    }
}

// ---------------- kernel 1: per-(patch,channel) grade partial ----------------
// One 32-lane group = one (patch, channel); 64-thread single-wave blocks
// (s_barrier lowers to waitcnt-only).  __launch_bounds__(64,4): occupancy is
// WG-slot-capped at 16 waves/CU = 4 waves/EU anyway, so allow 128 VGPRs —
// the default 64-VGPR budget was forcing scratch spills (VGPR pinned at 64
// across R4-R6 while live set needed ~80).
__global__ __launch_bounds__(64, 4) void k_grade(const float* __restrict__ x,
                                                 float* __restrict__ partial) {
    __shared__ __align__(16) float sS[2][32 * SST];
    __shared__ float sF[64];
    const int tid = threadIdx.x, g = tid >> 5, lane = tid & 31;
    sF[tid] = cF.f[tid];

    const int tc   = blockIdx.x * 2 + g;         // grid exact: 23064*2 = 46128
    const int task = tc / 3, c = tc - task * 3;
    const int b  = task / LPB;
    const int l  = task - b * LPB;
    const int ph = l / 31, pw = l - ph * 31;
    const float4* row = (const float4*)(x + (size_t)(b * 3 + c) * 262144
                                          + (ph * 16 + lane) * 512 + pw * 16);
    float* S = sS[g];

    // pass 1: U[r][j] = sum_k P[r][k] D[j][k]; lane = r, contiguous float4 row
    float p[32];
    #pragma unroll
    for (int q = 0; q < 8; ++q) {
        float4 f = row[q];
        p[4*q] = f.x; p[4*q+1] = f.y; p[4*q+2] = f.z; p[4*q+3] = f.w;
    }
    dct32(p, [&](int j, float acc) { S[j * SST + lane] = acc; });
    __syncthreads();                             // single-wave: waitcnt only

    // pass 2: lane = column of U; transposed read as 16 x ds_read_b64
    float u[32];
    #pragma unroll
    for (int h = 0; h < 16; ++h) {
        float2 uu = *(const float2*)&S[lane * SST + 2 * h];
        u[2*h] = uu.x; u[2*h+1] = uu.y;
    }
    float gsum = 0.0f;
    dct32(u, [&](int i, float z) {
        gsum = fmaf(__log2f(fabsf(z) + 1.0f), sF[i + lane], gsum);  // ln2 in sF
    });
    #pragma unroll
    for (int off = 16; off > 0; off >>= 1) gsum += __shfl_down(gsum, off, 32);
    if (lane == 0) partial[tc] = gsum;
}

// ---------------- kernel 2: fused select + gather ----------------
// Block b: sum 3 channel partials (deterministic order), top-2/bottom-2 via
// u64 key = grade_bits<<32 | idx (matches stable-argsort tie semantics), then
// copy the 4 selected raw patches (level_y == patches: LEVEL_FILT all-ones,
// D orthonormal).
__global__ __launch_bounds__(256) void k_selgather(const float* __restrict__ partial,
                                                   const float* __restrict__ x,
                                                   float* __restrict__ out) {
    __shared__ unsigned long long smx1[256], smx2[256], smn1[256], smn2[256];
    __shared__ int ssel[4];
    const int b = blockIdx.x, tid = threadIdx.x;
    unsigned long long mx1 = 0, mx2 = 0, mn1 = ~0ULL, mn2 = ~0ULL;
    for (int l = tid; l < LPB; l += 256) {
        const float* pp = partial + (size_t)(b * LPB + l) * 3;
        float gr = pp[0] + pp[1] + pp[2];
        unsigned int bits = __float_as_uint(gr);
        unsigned long long k = ((unsigned long long)bits << 32) | (unsigned int)l;
        if (k > mx1) { mx2 = mx1; mx1 = k; } else if (k > mx2) { mx2 = k; }
        if (k < mn1) { mn2 = mn1; mn1 = k; } else if (k < mn2) { mn2 = k; }
    }
    smx1[tid] = mx1; smx2[tid] = mx2; smn1[tid] = mn1; smn2[tid] = mn2;
    for (int off = 128; off > 0; off >>= 1) {
        __syncthreads();
        if (tid < off) {
            unsigned long long a1 = smx1[tid], a2 = smx2[tid], b1 = smx1[tid + off], b2 = smx2[tid + off];
            unsigned long long lo = a1 < b1 ? a1 : b1, hi = a1 < b1 ? b1 : a1;
            unsigned long long c2 = a2 > b2 ? a2 : b2;
            smx1[tid] = hi; smx2[tid] = lo > c2 ? lo : c2;
            a1 = smn1[tid]; a2 = smn2[tid]; b1 = smn1[tid + off]; b2 = smn2[tid + off];
            lo = a1 < b1 ? a1 : b1; hi = a1 < b1 ? b1 : a1;
            c2 = a2 < b2 ? a2 : b2;
            smn1[tid] = lo; smn2[tid] = hi < c2 ? hi : c2;
        }
    }
    __syncthreads();
    if (tid == 0) {
        ssel[0] = (int)(smn1[0] & 0xffffffffu);  // x_minmin
        ssel[1] = (int)(smx1[0] & 0xffffffffu);  // x_maxmax
        ssel[2] = (int)(smn2[0] & 0xffffffffu);  // x_minmin1
        ssel[3] = (int)(smx2[0] & 0xffffffffu);  // x_maxmax1
    }
    __syncthreads();

    // gather: 4 outputs x 3 ch x 32 x 32 floats = 3072 float4 per batch
    #pragma unroll
    for (int it = 0; it < 12; ++it) {
        const int q  = it * 256 + tid;           // [0, 3072)
        const int o  = q / 768;
        const int r2 = q - o * 768;
        const int c  = r2 >> 8;
        const int p  = r2 & 255;
        const int i  = p >> 3, j4 = p & 7;
        const int l  = ssel[o];
        const int r0 = (l / 31) * 16, c0 = (l - (l / 31) * 31) * 16;
        const float4 v = *(const float4*)(x + ((size_t)(b * 3 + c) * 512 + r0 + i) * 512 + c0 + 4 * j4);
        *(float4*)(out + (size_t)o * 49152 + b * 3072 + c * 1024 + i * 32 + 4 * j4) = v;
    }
}

extern "C" void kernel_launch(void* const* d_in, const int* in_sizes, int n_in,
                              void* d_out, int out_size, void* d_ws, size_t ws_size,
                              hipStream_t stream) {
    const float* x = (const float*)d_in[0];
    float* out     = (float*)d_out;
    float* partial = (float*)d_ws;               // NPC floats (184 KB)
    k_grade    <<<NPC / 2, 64, 0, stream>>>(x, partial);
    k_selgather<<<16,     256, 0, stream>>>(partial, x, out);
}